// Round 2
// baseline (567.403 us; speedup 1.0000x reference)
//
#include <hip/hip_runtime.h>

__device__ __forceinline__ float frcp(float x){ return __builtin_amdgcn_rcpf(x); }
__device__ __forceinline__ float fexp2(float x){ return exp2f(x); }
// sigmoid(x) = 1/(1+e^-x);  tanh(x) = 1 - 2/(e^{2x}+1)
__device__ __forceinline__ float sigf(float x){ return frcp(1.f + fexp2(-1.4426950408889634f*x)); }
__device__ __forceinline__ float tanh_(float x){ return 1.f - 2.f*frcp(1.f + fexp2(2.8853900817779268f*x)); }

// ---------------- embedding gather + concat -> x[b*128+t][128] fp32 ----------------
__global__ __launch_bounds__(256) void embed_kernel(
    const int* __restrict__ widx, const int* __restrict__ pidx,
    const float* __restrict__ wemb, const float* __restrict__ temb,
    float* __restrict__ x)
{
    int gid = blockIdx.x*256 + threadIdx.x;   // 262144 total
    int bt = gid >> 7, c = gid & 127;
    float v;
    if (c < 100) v = wemb[(size_t)widx[bt]*100 + c];
    else         v = temb[(size_t)pidx[bt]*28 + (c-100)];
    x[gid] = v;
}

// ---------------- w2[k] = -2*fc2_w[k]; S = sum(fc2_w) + fc2_b ----------------
__global__ void prep_kernel(const float* __restrict__ fc2w, const float* __restrict__ fc2b,
                            float* __restrict__ w2, float* __restrict__ Sp)
{
    __shared__ float red[128];
    int t = threadIdx.x;
    float w = (t < 100) ? fc2w[t] : 0.f;
    if (t < 100) w2[t] = -2.f*w;
    red[t] = w;
    __syncthreads();
    for (int s = 64; s > 0; s >>= 1) {
        if (t < s) red[t] += red[t+s];
        __syncthreads();
    }
    if (t == 0) Sp[0] = red[0] + fc2b[0];
}

// ---------------- generic C[m][n] = sum_k A[m][k]*B[n][k] (+biases) (opt exp(2x)) --------
// M fixed 2048 (grid.x=16, BM=128). grid.z selects B/bias/C set. BN=64, BK=16.
__global__ __launch_bounds__(256) void gemm_kernel(
    const float* __restrict__ A, int K,
    const float* __restrict__ B0, const float* __restrict__ B1, int ldb,
    const float* __restrict__ bias0a, const float* __restrict__ bias0b,
    const float* __restrict__ bias1a, const float* __restrict__ bias1b,
    float* __restrict__ C0, float* __restrict__ C1, int ldc, int N,
    int expflag)
{
    __shared__ float As[16][132];   // [k][m], pad 132 (16B-aligned rows)
    __shared__ float Bs[16][68];    // [k][n]
    const int z = blockIdx.z;
    const float* B  = z ? B1 : B0;
    const float* ba = z ? bias1a : bias0a;
    const float* bb = z ? bias1b : bias0b;
    float* C = z ? C1 : C0;
    const int m0 = blockIdx.x * 128;
    const int n0 = blockIdx.y * 64;
    const int tx = threadIdx.x;
    const int tm = tx & 15, tn = tx >> 4;       // 8x4 micro-tile
    const int arow = tx >> 1, akq = (tx & 1) * 8;
    const int brow = tx >> 2, bkq = (tx & 3) * 4;
    float acc[8][4];
    #pragma unroll
    for (int r=0;r<8;++r){
        #pragma unroll
        for (int c=0;c<4;++c) acc[r][c]=0.f; }
    for (int k0 = 0; k0 < K; k0 += 16) {
        const float* ap = A + (size_t)(m0+arow)*K + k0 + akq;
        float4 a0 = *(const float4*)ap;
        float4 a1 = *(const float4*)(ap+4);
        float4 bv = make_float4(0.f,0.f,0.f,0.f);
        if (n0 + brow < N) {
            const float* bp = B + (size_t)(n0+brow)*ldb + k0 + bkq;
            bv = *(const float4*)bp;
        }
        __syncthreads();
        As[akq+0][arow]=a0.x; As[akq+1][arow]=a0.y; As[akq+2][arow]=a0.z; As[akq+3][arow]=a0.w;
        As[akq+4][arow]=a1.x; As[akq+5][arow]=a1.y; As[akq+6][arow]=a1.z; As[akq+7][arow]=a1.w;
        Bs[bkq+0][brow]=bv.x; Bs[bkq+1][brow]=bv.y; Bs[bkq+2][brow]=bv.z; Bs[bkq+3][brow]=bv.w;
        __syncthreads();
        #pragma unroll
        for (int kk = 0; kk < 16; ++kk) {
            float4 av0 = *(const float4*)&As[kk][tm*8];
            float4 av1 = *(const float4*)&As[kk][tm*8+4];
            float4 bvv = *(const float4*)&Bs[kk][tn*4];
            float a[8] = {av0.x,av0.y,av0.z,av0.w,av1.x,av1.y,av1.z,av1.w};
            float b[4] = {bvv.x,bvv.y,bvv.z,bvv.w};
            #pragma unroll
            for (int r=0;r<8;++r){
                #pragma unroll
                for (int c=0;c<4;++c)
                    acc[r][c] = fmaf(a[r], b[c], acc[r][c]);
            }
        }
    }
    float bias[4];
    #pragma unroll
    for (int c=0;c<4;++c) {
        int n = n0 + tn*4 + c;
        float v = 0.f;
        if (n < N) {
            if (ba) v += ba[n];
            if (bb) v += bb[n];
        }
        bias[c] = v;
    }
    #pragma unroll
    for (int r=0;r<8;++r) {
        int m = m0 + tm*8 + r;
        float v[4];
        #pragma unroll
        for (int c=0;c<4;++c) {
            float t = acc[r][c] + bias[c];
            if (expflag) t = fexp2(fminf(fmaxf(t,-40.f),40.f)*2.8853900817779268f); // e^{2t}
            v[c] = t;
        }
        int n = n0 + tn*4;
        if (n + 3 < N) {
            float4 st; st.x=v[0]; st.y=v[1]; st.z=v[2]; st.w=v[3];
            *(float4*)&C[(size_t)m*ldc + n] = st;
        } else {
            #pragma unroll
            for (int c=0;c<4;++c) if (n+c < N) C[(size_t)m*ldc + n + c] = v[c];
        }
    }
}

// ---------------- LSTM: one block per (b, dir); w_hh row t resident in VGPRs -------------
__global__ __launch_bounds__(512, 2) void lstm_kernel(
    const float* __restrict__ xp,      // [dir][2048][512] precomputed x@W_ih^T + b_ih + b_hh
    const float* __restrict__ whh_f, const float* __restrict__ whh_b,
    float* __restrict__ hcat)          // [16][128][256]
{
    const int b = blockIdx.x & 15;
    const int dir = blockIdx.x >> 4;
    const int t = threadIdx.x;         // gate row 0..511
    const float* whh = dir ? whh_b : whh_f;
    float w[128];
    {
        const float* wr = whh + (size_t)t*128;
        #pragma unroll
        for (int j = 0; j < 128; j += 4) {
            float4 u = *(const float4*)(wr + j);
            w[j+0]=u.x; w[j+1]=u.y; w[j+2]=u.z; w[j+3]=u.w;
        }
    }
    __shared__ float h_lds[128];
    __shared__ float g_lds[512];
    float c = 0.f;
    if (t < 128) h_lds[t] = 0.f;
    __syncthreads();
    const float* xpd = xp + (size_t)dir*(2048*512) + (size_t)b*(128*512);
    for (int s = 0; s < 128; ++s) {
        const int ts = dir ? (127 - s) : s;
        float xpv = xpd[ts*512 + t];
        float a0=0.f,a1=0.f,a2=0.f,a3=0.f;   // 4 chains to hide FMA latency
        #pragma unroll
        for (int j = 0; j < 128; j += 4) {
            float4 h4 = *(const float4*)&h_lds[j];   // broadcast reads
            a0 = fmaf(w[j+0], h4.x, a0);
            a1 = fmaf(w[j+1], h4.y, a1);
            a2 = fmaf(w[j+2], h4.z, a2);
            a3 = fmaf(w[j+3], h4.w, a3);
        }
        g_lds[t] = xpv + ((a0+a1)+(a2+a3));
        __syncthreads();
        if (t < 128) {
            float gi = g_lds[t], gf = g_lds[128+t], gg = g_lds[256+t], go = g_lds[384+t];
            c = sigf(gf)*c + sigf(gi)*tanh_(gg);
            float h = sigf(go)*tanh_(c);
            h_lds[t] = h;
            hcat[((size_t)b*128 + ts)*256 + dir*128 + t] = h;
        }
        __syncthreads();
    }
}

// ------------- pairwise scorer: out[(i*128+j)*16+b] = S + sum_k w2_k / (ea_ik*eb_jk + 1) ----
__global__ __launch_bounds__(256) void pair_kernel(
    const float* __restrict__ ea, const float* __restrict__ eb,
    const float* __restrict__ w2, const float* __restrict__ Sp,
    float* __restrict__ out)
{
    __shared__ float eas[32][100];
    __shared__ float ebs[32][100];
    __shared__ float w2s[100];
    const int it = blockIdx.x * 32, jt = blockIdx.y * 32, b = blockIdx.z;
    const int tx = threadIdx.x;
    const float* eab = ea + (size_t)b*12800;
    const float* ebb = eb + (size_t)b*12800;
    for (int idx = tx; idx < 3200; idx += 256) {
        int r = idx / 100;
        int cc = idx - r*100;
        eas[r][cc] = eab[(it + r)*100 + cc];
        ebs[r][cc] = ebb[(jt + r)*100 + cc];
    }
    if (tx < 100) w2s[tx] = w2[tx];
    const float S = Sp[0];
    __syncthreads();
    const int jp = tx & 15, ip = tx >> 4;
    const int i0 = ip*2, j0 = jp*2;
    float acc00=S, acc01=S, acc10=S, acc11=S;
    #pragma unroll
    for (int k = 0; k < 100; k += 4) {
        float4 A0 = *(const float4*)&eas[i0][k];
        float4 A1 = *(const float4*)&eas[i0+1][k];
        float4 B0 = *(const float4*)&ebs[j0][k];
        float4 B1 = *(const float4*)&ebs[j0+1][k];
        float4 W  = *(const float4*)&w2s[k];
        acc00 = fmaf(W.x, frcp(fmaf(A0.x,B0.x,1.f)), acc00);
        acc01 = fmaf(W.x, frcp(fmaf(A0.x,B1.x,1.f)), acc01);
        acc10 = fmaf(W.x, frcp(fmaf(A1.x,B0.x,1.f)), acc10);
        acc11 = fmaf(W.x, frcp(fmaf(A1.x,B1.x,1.f)), acc11);
        acc00 = fmaf(W.y, frcp(fmaf(A0.y,B0.y,1.f)), acc00);
        acc01 = fmaf(W.y, frcp(fmaf(A0.y,B1.y,1.f)), acc01);
        acc10 = fmaf(W.y, frcp(fmaf(A1.y,B0.y,1.f)), acc10);
        acc11 = fmaf(W.y, frcp(fmaf(A1.y,B1.y,1.f)), acc11);
        acc00 = fmaf(W.z, frcp(fmaf(A0.z,B0.z,1.f)), acc00);
        acc01 = fmaf(W.z, frcp(fmaf(A0.z,B1.z,1.f)), acc01);
        acc10 = fmaf(W.z, frcp(fmaf(A1.z,B0.z,1.f)), acc10);
        acc11 = fmaf(W.z, frcp(fmaf(A1.z,B1.z,1.f)), acc11);
        acc00 = fmaf(W.w, frcp(fmaf(A0.w,B0.w,1.f)), acc00);
        acc01 = fmaf(W.w, frcp(fmaf(A0.w,B1.w,1.f)), acc01);
        acc10 = fmaf(W.w, frcp(fmaf(A1.w,B0.w,1.f)), acc10);
        acc11 = fmaf(W.w, frcp(fmaf(A1.w,B1.w,1.f)), acc11);
    }
    const int gi0 = it + i0, gj0 = jt + j0;
    out[((size_t)(gi0  )*128 + gj0  )*16 + b] = acc00;
    out[((size_t)(gi0  )*128 + gj0+1)*16 + b] = acc01;
    out[((size_t)(gi0+1)*128 + gj0  )*16 + b] = acc10;
    out[((size_t)(gi0+1)*128 + gj0+1)*16 + b] = acc11;
}

extern "C" void kernel_launch(void* const* d_in, const int* in_sizes, int n_in,
                              void* d_out, int out_size, void* d_ws, size_t ws_size,
                              hipStream_t stream)
{
    (void)in_sizes; (void)n_in; (void)out_size; (void)ws_size;
    const int*   widx = (const int*)d_in[0];
    const int*   pidx = (const int*)d_in[1];
    const float* wemb = (const float*)d_in[4];
    const float* temb = (const float*)d_in[5];
    const float* w_ih_l0f = (const float*)d_in[6];
    const float* w_hh_l0f = (const float*)d_in[7];
    const float* b_ih_l0f = (const float*)d_in[8];
    const float* b_hh_l0f = (const float*)d_in[9];
    const float* w_ih_l0b = (const float*)d_in[10];
    const float* w_hh_l0b = (const float*)d_in[11];
    const float* b_ih_l0b = (const float*)d_in[12];
    const float* b_hh_l0b = (const float*)d_in[13];
    const float* w_ih_l1f = (const float*)d_in[14];
    const float* w_hh_l1f = (const float*)d_in[15];
    const float* b_ih_l1f = (const float*)d_in[16];
    const float* b_hh_l1f = (const float*)d_in[17];
    const float* w_ih_l1b = (const float*)d_in[18];
    const float* w_hh_l1b = (const float*)d_in[19];
    const float* b_ih_l1b = (const float*)d_in[20];
    const float* b_hh_l1b = (const float*)d_in[21];
    const float* fc1_w = (const float*)d_in[22];
    const float* fc1_b = (const float*)d_in[23];
    const float* fc2_w = (const float*)d_in[24];
    const float* fc2_b = (const float*)d_in[25];

    float* ws  = (float*)d_ws;
    float* x   = ws;                  // 262144
    float* xp0 = x + 262144;          // 2 * 1048576
    float* h1  = xp0 + 2097152;       // 524288
    float* xp1 = h1 + 524288;         // 2 * 1048576
    float* h2  = xp1 + 2097152;       // 524288
    float* ea  = h2 + 524288;         // 204800
    float* eb  = ea + 204800;         // 204800
    float* w2  = eb + 204800;         // 128
    float* Sp  = w2 + 128;            // 1
    // total ~5.92M floats = 23.7 MB

    embed_kernel<<<1024, 256, 0, stream>>>(widx, pidx, wemb, temb, x);
    prep_kernel<<<1, 128, 0, stream>>>(fc2_w, fc2_b, w2, Sp);
    // layer 0 input projections (both dirs in grid.z)
    gemm_kernel<<<dim3(16,8,2), 256, 0, stream>>>(x, 128,
        w_ih_l0f, w_ih_l0b, 128,
        b_ih_l0f, b_hh_l0f, b_ih_l0b, b_hh_l0b,
        xp0, xp0 + 1048576, 512, 512, 0);
    lstm_kernel<<<32, 512, 0, stream>>>(xp0, w_hh_l0f, w_hh_l0b, h1);
    // layer 1 input projections
    gemm_kernel<<<dim3(16,8,2), 256, 0, stream>>>(h1, 256,
        w_ih_l1f, w_ih_l1b, 256,
        b_ih_l1f, b_hh_l1f, b_ih_l1b, b_hh_l1b,
        xp1, xp1 + 1048576, 512, 512, 0);
    lstm_kernel<<<32, 512, 0, stream>>>(xp1, w_hh_l1f, w_hh_l1b, h2);
    // fc1: a = h2@wa^T -> ea = exp(2a); bp = h2@wb^T + fc1_b -> eb = exp(2bp)
    gemm_kernel<<<dim3(16,2,2), 256, 0, stream>>>(h2, 256,
        fc1_w, fc1_w + 256, 512,
        nullptr, nullptr, fc1_b, nullptr,
        ea, eb, 100, 100, 1);
    pair_kernel<<<dim3(4,4,16), 256, 0, stream>>>(ea, eb, w2, Sp, (float*)d_out);
}

// Round 3
// 454.210 us; speedup vs baseline: 1.2492x; 1.2492x over previous
//
#include <hip/hip_runtime.h>

__device__ __forceinline__ float frcp(float x){ return __builtin_amdgcn_rcpf(x); }
__device__ __forceinline__ float fexp2(float x){ return __builtin_amdgcn_exp2f(x); }
// sigmoid(x) = 1/(1+e^-x);  tanh(x) = 1 - 2/(e^{2x}+1)
__device__ __forceinline__ float sigf(float x){ return frcp(1.f + fexp2(-1.4426950408889634f*x)); }
__device__ __forceinline__ float tanh_(float x){ return 1.f - 2.f*frcp(1.f + fexp2(2.8853900817779268f*x)); }

// ---------------- embedding gather + concat -> x[b*128+t][128] fp32 ----------------
__global__ __launch_bounds__(256) void embed_kernel(
    const int* __restrict__ widx, const int* __restrict__ pidx,
    const float* __restrict__ wemb, const float* __restrict__ temb,
    float* __restrict__ x)
{
    int gid = blockIdx.x*256 + threadIdx.x;   // 262144 total
    int bt = gid >> 7, c = gid & 127;
    float v;
    if (c < 100) v = wemb[(size_t)widx[bt]*100 + c];
    else         v = temb[(size_t)pidx[bt]*28 + (c-100)];
    x[gid] = v;
}

// ---------------- w2[k] = -2*fc2_w[k]; S = sum(fc2_w) + fc2_b ----------------
__global__ void prep_kernel(const float* __restrict__ fc2w, const float* __restrict__ fc2b,
                            float* __restrict__ w2, float* __restrict__ Sp)
{
    __shared__ float red[128];
    int t = threadIdx.x;
    float w = (t < 100) ? fc2w[t] : 0.f;
    if (t < 100) w2[t] = -2.f*w;
    red[t] = w;
    __syncthreads();
    for (int s = 64; s > 0; s >>= 1) {
        if (t < s) red[t] += red[t+s];
        __syncthreads();
    }
    if (t == 0) Sp[0] = red[0] + fc2b[0];
}

// ---------------- generic C[m][n] = sum_k A[m][k]*B[n][k] (+biases) (opt exp(2x)) --------
// M fixed 2048 (grid.x=16, BM=128). grid.z selects B/bias/C set. BN=64, BK=16.
// permflag: output column p holds gate-row gr(p) = (p&3)*128 + (p>>2) (for LSTM layout).
__global__ __launch_bounds__(256) void gemm_kernel(
    const float* __restrict__ A, int K,
    const float* __restrict__ B0, const float* __restrict__ B1, int ldb,
    const float* __restrict__ bias0a, const float* __restrict__ bias0b,
    const float* __restrict__ bias1a, const float* __restrict__ bias1b,
    float* __restrict__ C0, float* __restrict__ C1, int ldc, int N,
    int expflag, int permflag)
{
    __shared__ float As[16][132];   // [k][m], pad 132 (16B-aligned rows)
    __shared__ float Bs[16][68];    // [k][n]
    const int z = blockIdx.z;
    const float* B  = z ? B1 : B0;
    const float* ba = z ? bias1a : bias0a;
    const float* bb = z ? bias1b : bias0b;
    float* C = z ? C1 : C0;
    const int m0 = blockIdx.x * 128;
    const int n0 = blockIdx.y * 64;
    const int tx = threadIdx.x;
    const int tm = tx & 15, tn = tx >> 4;       // 8x4 micro-tile
    const int arow = tx >> 1, akq = (tx & 1) * 8;
    const int brow = tx >> 2, bkq = (tx & 3) * 4;
    float acc[8][4];
    #pragma unroll
    for (int r=0;r<8;++r){
        #pragma unroll
        for (int c=0;c<4;++c) acc[r][c]=0.f; }
    const int bn = n0 + brow;
    const int brow_src = permflag ? ((bn & 3)*128 + (bn >> 2)) : bn;
    for (int k0 = 0; k0 < K; k0 += 16) {
        const float* ap = A + (size_t)(m0+arow)*K + k0 + akq;
        float4 a0 = *(const float4*)ap;
        float4 a1 = *(const float4*)(ap+4);
        float4 bv = make_float4(0.f,0.f,0.f,0.f);
        if (bn < N) {
            const float* bp = B + (size_t)brow_src*ldb + k0 + bkq;
            bv = *(const float4*)bp;
        }
        __syncthreads();
        As[akq+0][arow]=a0.x; As[akq+1][arow]=a0.y; As[akq+2][arow]=a0.z; As[akq+3][arow]=a0.w;
        As[akq+4][arow]=a1.x; As[akq+5][arow]=a1.y; As[akq+6][arow]=a1.z; As[akq+7][arow]=a1.w;
        Bs[bkq+0][brow]=bv.x; Bs[bkq+1][brow]=bv.y; Bs[bkq+2][brow]=bv.z; Bs[bkq+3][brow]=bv.w;
        __syncthreads();
        #pragma unroll
        for (int kk = 0; kk < 16; ++kk) {
            float4 av0 = *(const float4*)&As[kk][tm*8];
            float4 av1 = *(const float4*)&As[kk][tm*8+4];
            float4 bvv = *(const float4*)&Bs[kk][tn*4];
            float a[8] = {av0.x,av0.y,av0.z,av0.w,av1.x,av1.y,av1.z,av1.w};
            float b[4] = {bvv.x,bvv.y,bvv.z,bvv.w};
            #pragma unroll
            for (int r=0;r<8;++r){
                #pragma unroll
                for (int c=0;c<4;++c)
                    acc[r][c] = fmaf(a[r], b[c], acc[r][c]);
            }
        }
    }
    float bias[4];
    #pragma unroll
    for (int c=0;c<4;++c) {
        int n = n0 + tn*4 + c;
        int nsrc = permflag ? ((n & 3)*128 + (n >> 2)) : n;
        float v = 0.f;
        if (n < N) {
            if (ba) v += ba[nsrc];
            if (bb) v += bb[nsrc];
        }
        bias[c] = v;
    }
    #pragma unroll
    for (int r=0;r<8;++r) {
        int m = m0 + tm*8 + r;
        float v[4];
        #pragma unroll
        for (int c=0;c<4;++c) {
            float t = acc[r][c] + bias[c];
            if (expflag) t = fexp2(fminf(fmaxf(t,-40.f),40.f)*2.8853900817779268f); // e^{2t}
            v[c] = t;
        }
        int n = n0 + tn*4;
        if (n + 3 < N) {
            float4 st; st.x=v[0]; st.y=v[1]; st.z=v[2]; st.w=v[3];
            *(float4*)&C[(size_t)m*ldc + n] = st;
        } else {
            #pragma unroll
            for (int c=0;c<4;++c) if (n+c < N) C[(size_t)m*ldc + n + c] = v[c];
        }
    }
}

// ---------------- LSTM: one block per (b, dir); gate-interleaved thread map ----------------
// thread t: row r = t>>2, gate g = t&3 (i,f,g,o). Weight row gr = g*128 + r resident in VGPRs.
// xp comes in pre-permuted (col p = gate row gr(p)). One barrier per step; h double-buffered.
__global__ __launch_bounds__(512)
__attribute__((amdgpu_waves_per_eu(2,2)))
void lstm_kernel(
    const float* __restrict__ xp,      // [dir][2048][512] permuted cols
    const float* __restrict__ whh_f, const float* __restrict__ whh_b,
    float* __restrict__ hcat)          // [16][128][256]
{
    const int b = blockIdx.x & 15;
    const int dir = blockIdx.x >> 4;
    const int t = threadIdx.x;
    const int gate = t & 3, r = t >> 2;
    const int lane = t & 63, qbase = lane & ~3;
    const float* whh = dir ? whh_b : whh_f;
    // per-lane activation constants: sig(x)=1/(1+2^(-x*log2e)); tanh(x)=1-2/(1+2^(2x*log2e))
    const float kexp = (gate == 2) ? 2.8853900817779268f : -1.4426950408889634f;
    const float mA   = (gate == 2) ? -2.f : 1.f;
    const float mB   = (gate == 2) ?  1.f : 0.f;
    float w[128];
    {
        const float* wr = whh + (size_t)(gate*128 + r)*128;
        #pragma unroll
        for (int j = 0; j < 128; j += 4) {
            float4 u = *(const float4*)(wr + j);
            w[j+0]=u.x; w[j+1]=u.y; w[j+2]=u.z; w[j+3]=u.w;
        }
    }
    __shared__ float h_lds[2][128];
    float c = 0.f;
    if (t < 128) h_lds[0][t] = 0.f;
    __syncthreads();
    const float* xpd = xp + (size_t)dir*(2048*512) + (size_t)b*(128*512);
    for (int s = 0; s < 128; ++s) {
        const int ts = dir ? (127 - s) : s;
        float xpv = xpd[ts*512 + t];
        const float* hb = h_lds[s & 1];
        float a0=0.f,a1=0.f,a2=0.f,a3=0.f;
        #pragma unroll
        for (int j = 0; j < 128; j += 4) {
            float4 h4 = *(const float4*)&hb[j];   // broadcast reads
            a0 = fmaf(w[j+0], h4.x, a0);
            a1 = fmaf(w[j+1], h4.y, a1);
            a2 = fmaf(w[j+2], h4.z, a2);
            a3 = fmaf(w[j+3], h4.w, a3);
        }
        float dot = xpv + ((a0+a1)+(a2+a3));
        // activated gate value (sig for i,f,o; tanh for g)
        float act = fmaf(mA, frcp(1.f + fexp2(kexp*dot)), mB);
        // quad broadcast: every lane of the quad gets all 4 activated gates
        float i_ = __shfl(act, qbase+0, 64);
        float f_ = __shfl(act, qbase+1, 64);
        float g_ = __shfl(act, qbase+2, 64);
        float o_ = __shfl(act, qbase+3, 64);
        c = f_*c + i_*g_;                  // redundant in all 4 lanes, consistent
        float h = o_ * tanh_(c);
        if (gate == 0) {
            h_lds[(s & 1) ^ 1][r] = h;
            hcat[((size_t)b*128 + ts)*256 + dir*128 + r] = h;
        }
        __syncthreads();
    }
}

// ------------- pairwise scorer: out[(i*128+j)*16+b] = S + sum_k w2_k / (ea_ik*eb_jk + 1) ----
__global__ __launch_bounds__(256) void pair_kernel(
    const float* __restrict__ ea, const float* __restrict__ eb,
    const float* __restrict__ w2, const float* __restrict__ Sp,
    float* __restrict__ out)
{
    __shared__ float eas[32][100];
    __shared__ float ebs[32][100];
    __shared__ float w2s[100];
    const int it = blockIdx.x * 32, jt = blockIdx.y * 32, b = blockIdx.z;
    const int tx = threadIdx.x;
    const float* eab = ea + (size_t)b*12800;
    const float* ebb = eb + (size_t)b*12800;
    for (int idx = tx; idx < 3200; idx += 256) {
        int r = idx / 100;
        int cc = idx - r*100;
        eas[r][cc] = eab[(it + r)*100 + cc];
        ebs[r][cc] = ebb[(jt + r)*100 + cc];
    }
    if (tx < 100) w2s[tx] = w2[tx];
    const float S = Sp[0];
    __syncthreads();
    const int jp = tx & 15, ip = tx >> 4;
    const int i0 = ip*2, j0 = jp*2;
    float acc00=S, acc01=S, acc10=S, acc11=S;
    #pragma unroll
    for (int k = 0; k < 100; k += 4) {
        float4 A0 = *(const float4*)&eas[i0][k];
        float4 A1 = *(const float4*)&eas[i0+1][k];
        float4 B0 = *(const float4*)&ebs[j0][k];
        float4 B1 = *(const float4*)&ebs[j0+1][k];
        float4 W  = *(const float4*)&w2s[k];
        acc00 = fmaf(W.x, frcp(fmaf(A0.x,B0.x,1.f)), acc00);
        acc01 = fmaf(W.x, frcp(fmaf(A0.x,B1.x,1.f)), acc01);
        acc10 = fmaf(W.x, frcp(fmaf(A1.x,B0.x,1.f)), acc10);
        acc11 = fmaf(W.x, frcp(fmaf(A1.x,B1.x,1.f)), acc11);
        acc00 = fmaf(W.y, frcp(fmaf(A0.y,B0.y,1.f)), acc00);
        acc01 = fmaf(W.y, frcp(fmaf(A0.y,B1.y,1.f)), acc01);
        acc10 = fmaf(W.y, frcp(fmaf(A1.y,B0.y,1.f)), acc10);
        acc11 = fmaf(W.y, frcp(fmaf(A1.y,B1.y,1.f)), acc11);
        acc00 = fmaf(W.z, frcp(fmaf(A0.z,B0.z,1.f)), acc00);
        acc01 = fmaf(W.z, frcp(fmaf(A0.z,B1.z,1.f)), acc01);
        acc10 = fmaf(W.z, frcp(fmaf(A1.z,B0.z,1.f)), acc10);
        acc11 = fmaf(W.z, frcp(fmaf(A1.z,B1.z,1.f)), acc11);
        acc00 = fmaf(W.w, frcp(fmaf(A0.w,B0.w,1.f)), acc00);
        acc01 = fmaf(W.w, frcp(fmaf(A0.w,B1.w,1.f)), acc01);
        acc10 = fmaf(W.w, frcp(fmaf(A1.w,B0.w,1.f)), acc10);
        acc11 = fmaf(W.w, frcp(fmaf(A1.w,B1.w,1.f)), acc11);
    }
    const int gi0 = it + i0, gj0 = jt + j0;
    out[((size_t)(gi0  )*128 + gj0  )*16 + b] = acc00;
    out[((size_t)(gi0  )*128 + gj0+1)*16 + b] = acc01;
    out[((size_t)(gi0+1)*128 + gj0  )*16 + b] = acc10;
    out[((size_t)(gi0+1)*128 + gj0+1)*16 + b] = acc11;
}

extern "C" void kernel_launch(void* const* d_in, const int* in_sizes, int n_in,
                              void* d_out, int out_size, void* d_ws, size_t ws_size,
                              hipStream_t stream)
{
    (void)in_sizes; (void)n_in; (void)out_size; (void)ws_size;
    const int*   widx = (const int*)d_in[0];
    const int*   pidx = (const int*)d_in[1];
    const float* wemb = (const float*)d_in[4];
    const float* temb = (const float*)d_in[5];
    const float* w_ih_l0f = (const float*)d_in[6];
    const float* w_hh_l0f = (const float*)d_in[7];
    const float* b_ih_l0f = (const float*)d_in[8];
    const float* b_hh_l0f = (const float*)d_in[9];
    const float* w_ih_l0b = (const float*)d_in[10];
    const float* w_hh_l0b = (const float*)d_in[11];
    const float* b_ih_l0b = (const float*)d_in[12];
    const float* b_hh_l0b = (const float*)d_in[13];
    const float* w_ih_l1f = (const float*)d_in[14];
    const float* w_hh_l1f = (const float*)d_in[15];
    const float* b_ih_l1f = (const float*)d_in[16];
    const float* b_hh_l1f = (const float*)d_in[17];
    const float* w_ih_l1b = (const float*)d_in[18];
    const float* w_hh_l1b = (const float*)d_in[19];
    const float* b_ih_l1b = (const float*)d_in[20];
    const float* b_hh_l1b = (const float*)d_in[21];
    const float* fc1_w = (const float*)d_in[22];
    const float* fc1_b = (const float*)d_in[23];
    const float* fc2_w = (const float*)d_in[24];
    const float* fc2_b = (const float*)d_in[25];

    float* ws  = (float*)d_ws;
    float* x   = ws;                  // 262144
    float* xp0 = x + 262144;          // 2 * 1048576
    float* h1  = xp0 + 2097152;       // 524288
    float* xp1 = h1 + 524288;         // 2 * 1048576
    float* h2  = xp1 + 2097152;       // 524288
    float* ea  = h2 + 524288;         // 204800
    float* eb  = ea + 204800;         // 204800
    float* w2  = eb + 204800;         // 128
    float* Sp  = w2 + 128;            // 1
    // total ~5.92M floats = 23.7 MB

    embed_kernel<<<1024, 256, 0, stream>>>(widx, pidx, wemb, temb, x);
    prep_kernel<<<1, 128, 0, stream>>>(fc2_w, fc2_b, w2, Sp);
    // layer 0 input projections (both dirs in grid.z), gate-permuted columns
    gemm_kernel<<<dim3(16,8,2), 256, 0, stream>>>(x, 128,
        w_ih_l0f, w_ih_l0b, 128,
        b_ih_l0f, b_hh_l0f, b_ih_l0b, b_hh_l0b,
        xp0, xp0 + 1048576, 512, 512, 0, 1);
    lstm_kernel<<<32, 512, 0, stream>>>(xp0, w_hh_l0f, w_hh_l0b, h1);
    // layer 1 input projections, gate-permuted columns
    gemm_kernel<<<dim3(16,8,2), 256, 0, stream>>>(h1, 256,
        w_ih_l1f, w_ih_l1b, 256,
        b_ih_l1f, b_hh_l1f, b_ih_l1b, b_hh_l1b,
        xp1, xp1 + 1048576, 512, 512, 0, 1);
    lstm_kernel<<<32, 512, 0, stream>>>(xp1, w_hh_l1f, w_hh_l1b, h2);
    // fc1: a = h2@wa^T -> ea = exp(2a); bp = h2@wb^T + fc1_b -> eb = exp(2bp)
    gemm_kernel<<<dim3(16,2,2), 256, 0, stream>>>(h2, 256,
        fc1_w, fc1_w + 256, 512,
        nullptr, nullptr, fc1_b, nullptr,
        ea, eb, 100, 100, 1, 0);
    pair_kernel<<<dim3(4,4,16), 256, 0, stream>>>(ea, eb, w2, Sp, (float*)d_out);
}